// Round 1
// baseline (3692.497 us; speedup 1.0000x reference)
//
#include <hip/hip_runtime.h>
#include <math.h>

constexpr int TT = 32;      // T
constexpr int BB = 256;     // B
constexpr int HH = 384;     // HID
constexpr int GG = 1536;    // 4*HID
constexpr float LN_EPS = 1e-5f;

// ---------------------------------------------------------------------------
// Tiled fp32 GEMM: C[M,N] = A[M,K] @ B[K,N], row-major, 64x64 tile, BK=16,
// 256 threads, 4x4 micro-tile per thread. M%64==0, N%64==0, K%16==0 assumed.
// CONCAT=true: A is the virtual concat [ent(256) | spa(256) | sca(640)].
// ---------------------------------------------------------------------------
template<bool CONCAT>
__global__ __launch_bounds__(256)
void gemm64(const float* __restrict__ A,
            const float* __restrict__ Aent, const float* __restrict__ Aspa,
            const float* __restrict__ Asca,
            const float* __restrict__ B, float* __restrict__ C,
            int M, int K, int N)
{
    __shared__ float As[16][64];
    __shared__ float Bs[16][64];
    const int tid = threadIdx.x;
    const int bm = blockIdx.y * 64;
    const int bn = blockIdx.x * 64;
    const int tr = tid >> 4;        // 0..15
    const int tc = tid & 15;        // 0..15
    const int ar = tid >> 2;        // 0..63  (A tile row)
    const int ac = (tid & 3) * 4;   // 0,4,8,12 (A tile col)
    const int br = tid >> 4;        // 0..15  (B tile row)
    const int bc = (tid & 15) * 4;  // 0..60  (B tile col)

    float acc[4][4] = {};

    for (int k0 = 0; k0 < K; k0 += 16) {
        float4 av;
        const int arow = bm + ar;
        const int acol = k0 + ac;
        if (CONCAT) {
            const float* p;
            if (acol < 256)      p = Aent + arow * 256 + acol;
            else if (acol < 512) p = Aspa + arow * 256 + (acol - 256);
            else                 p = Asca + arow * 640 + (acol - 512);
            av = *reinterpret_cast<const float4*>(p);
        } else {
            av = *reinterpret_cast<const float4*>(A + arow * (long)K + acol);
        }
        As[ac + 0][ar] = av.x;
        As[ac + 1][ar] = av.y;
        As[ac + 2][ar] = av.z;
        As[ac + 3][ar] = av.w;
        *reinterpret_cast<float4*>(&Bs[br][bc]) =
            *reinterpret_cast<const float4*>(B + (k0 + br) * (long)N + bn + bc);
        __syncthreads();
        #pragma unroll
        for (int k = 0; k < 16; ++k) {
            const float4 a = *reinterpret_cast<const float4*>(&As[k][tr * 4]);
            const float4 b = *reinterpret_cast<const float4*>(&Bs[k][tc * 4]);
            acc[0][0] += a.x * b.x; acc[0][1] += a.x * b.y; acc[0][2] += a.x * b.z; acc[0][3] += a.x * b.w;
            acc[1][0] += a.y * b.x; acc[1][1] += a.y * b.y; acc[1][2] += a.y * b.z; acc[1][3] += a.y * b.w;
            acc[2][0] += a.z * b.x; acc[2][1] += a.z * b.y; acc[2][2] += a.z * b.z; acc[2][3] += a.z * b.w;
            acc[3][0] += a.w * b.x; acc[3][1] += a.w * b.y; acc[3][2] += a.w * b.z; acc[3][3] += a.w * b.w;
        }
        __syncthreads();
    }
    #pragma unroll
    for (int i = 0; i < 4; ++i) {
        float4 v = make_float4(acc[i][0], acc[i][1], acc[i][2], acc[i][3]);
        *reinterpret_cast<float4*>(C + (bm + tr * 4 + i) * (long)N + bn + tc * 4) = v;
    }
}

// ---------------------------------------------------------------------------
// Row LayerNorm over 1536 elements, in place: x = (x-mu)*rsqrt(var+eps)*g + b
// grid = #rows, block = 256 (each thread owns 6 strided elements)
// ---------------------------------------------------------------------------
__global__ __launch_bounds__(256)
void ln_rows(float* __restrict__ X, const float* __restrict__ g,
             const float* __restrict__ b)
{
    float* x = X + (long)blockIdx.x * GG;
    const int tid = threadIdx.x;
    float v[6];
    float s = 0.f, q = 0.f;
    #pragma unroll
    for (int i = 0; i < 6; ++i) {
        v[i] = x[tid + i * 256];
        s += v[i];
        q += v[i] * v[i];
    }
    #pragma unroll
    for (int o = 32; o; o >>= 1) {
        s += __shfl_xor(s, o);
        q += __shfl_xor(q, o);
    }
    __shared__ float red[2][4];
    const int wave = tid >> 6;
    if ((tid & 63) == 0) { red[0][wave] = s; red[1][wave] = q; }
    __syncthreads();
    float S = 0.f, Q = 0.f;
    #pragma unroll
    for (int w = 0; w < 4; ++w) { S += red[0][w]; Q += red[1][w]; }
    const float mean = S * (1.0f / GG);
    const float var  = Q * (1.0f / GG) - mean * mean;
    const float rs   = rsqrtf(var + LN_EPS);
    #pragma unroll
    for (int i = 0; i < 6; ++i) {
        const int col = tid + i * 256;
        x[col] = (v[i] - mean) * rs * g[col] + b[col];
    }
}

// ---------------------------------------------------------------------------
// Fused LSTM cell for one timestep:
//   gate = xg_t + LN(h@wh; ghw,ghb) + bias ; i,f,o,u = split(gate,4)
//   c = sig(f)*c_in + sig(i)*tanh(u) ; h = sig(o)*tanh(c)
// grid = B rows, block = 384 (thread j owns gates i_j, f_j, o_j, u_j)
// ---------------------------------------------------------------------------
__device__ __forceinline__ float sigm(float x) { return 1.0f / (1.0f + __expf(-x)); }

__global__ __launch_bounds__(384)
void lstm_cell(const float* __restrict__ tmp,   // [B, 1536] = h@wh (raw)
               const float* __restrict__ xg,    // [B, 1536] (t-slice, LN'd + scaled)
               const float* __restrict__ bias,  // [1536]
               const float* __restrict__ ghw,   // [1536]
               const float* __restrict__ ghb,   // [1536]
               const float* __restrict__ c_in,  // [B, 384]
               float* __restrict__ h_state,     // [B, 384]
               float* __restrict__ c_state,     // [B, 384]
               float* __restrict__ x_out,       // [B, 384] (this t's h output)
               float* __restrict__ hn_out,      // [B, 384] or written only if last
               float* __restrict__ cn_out,
               int is_last)
{
    const int b = blockIdx.x;
    const int j = threadIdx.x;  // 0..383
    const float* trow = tmp + (long)b * GG;

    float v[4];
    float s = 0.f, q = 0.f;
    #pragma unroll
    for (int p = 0; p < 4; ++p) {
        v[p] = trow[j + p * HH];
        s += v[p];
        q += v[p] * v[p];
    }
    #pragma unroll
    for (int o = 32; o; o >>= 1) {
        s += __shfl_xor(s, o);
        q += __shfl_xor(q, o);
    }
    __shared__ float red[2][8];
    const int wave = j >> 6;  // 0..5
    if ((j & 63) == 0) { red[0][wave] = s; red[1][wave] = q; }
    __syncthreads();
    float S = 0.f, Q = 0.f;
    #pragma unroll
    for (int w = 0; w < 6; ++w) { S += red[0][w]; Q += red[1][w]; }
    const float mean = S * (1.0f / GG);
    const float var  = Q * (1.0f / GG) - mean * mean;
    const float rs   = rsqrtf(var + LN_EPS);

    const float* xrow = xg + (long)b * GG;
    float gate[4];
    #pragma unroll
    for (int p = 0; p < 4; ++p) {
        const int col = j + p * HH;
        gate[p] = (v[p] - mean) * rs * ghw[col] + ghb[col] + xrow[col] + bias[col];
    }
    const float gi = gate[0], gf = gate[1], go = gate[2], gu = gate[3];
    const float c = sigm(gf) * c_in[(long)b * HH + j] + sigm(gi) * tanhf(gu);
    const float h = sigm(go) * tanhf(c);

    h_state[(long)b * HH + j] = h;
    c_state[(long)b * HH + j] = c;
    x_out[(long)b * HH + j]   = h;
    if (is_last) {
        hn_out[(long)b * HH + j] = h;
        cn_out[(long)b * HH + j] = c;
    }
}

// ---------------------------------------------------------------------------
extern "C" void kernel_launch(void* const* d_in, const int* in_sizes, int n_in,
                              void* d_out, int out_size, void* d_ws, size_t ws_size,
                              hipStream_t stream)
{
    const float* ent  = (const float*)d_in[0];   // [T,B,256]
    const float* spa  = (const float*)d_in[1];   // [T,B,256]
    const float* sca  = (const float*)d_in[2];   // [T,B,640]
    const float* h0   = (const float*)d_in[3];   // [L,B,H]
    const float* c0   = (const float*)d_in[4];   // [L,B,H]
    const float* wx[3] = { (const float*)d_in[5], (const float*)d_in[6], (const float*)d_in[7] };
    const float* wh   = (const float*)d_in[8];   // [L,H,4H]
    const float* bias = (const float*)d_in[9];   // [L,4H]
    const float* gxw  = (const float*)d_in[10];  // [L,4H]
    const float* gxb  = (const float*)d_in[11];
    const float* ghw  = (const float*)d_in[12];
    const float* ghb  = (const float*)d_in[13];

    float* out = (float*)d_out;
    float* out_x  = out;                            // [T,B,H]
    float* out_hn = out + (long)TT * BB * HH;       // [L,B,H]
    float* out_cn = out_hn + (long)3 * BB * HH;     // [L,B,H]

    // workspace layout (floats)
    float* ws = (float*)d_ws;
    float* xg      = ws;                         // [8192, 1536]
    float* xbufA   = xg + (long)TT * BB * GG;    // [8192, 384]
    float* xbufB   = xbufA + (long)TT * BB * HH; // [8192, 384]
    float* tmp     = xbufB + (long)TT * BB * HH; // [256, 1536]
    float* h_state = tmp + (long)BB * GG;        // [256, 384]
    float* c_state = h_state + (long)BB * HH;    // [256, 384]

    const int M = TT * BB;  // 8192

    for (int l = 0; l < 3; ++l) {
        const int K = (l == 0) ? 1152 : HH;
        const float* xin = (l == 1) ? xbufA : xbufB;  // unused for l==0
        float* xout = (l == 0) ? xbufA : (l == 1) ? xbufB : out_x;

        // input projection: xg = x_l @ wx_l   [8192,K]x[K,1536]
        {
            dim3 grid(GG / 64, M / 64);
            if (l == 0)
                gemm64<true><<<grid, 256, 0, stream>>>(nullptr, ent, spa, sca,
                                                       wx[0], xg, M, K, GG);
            else
                gemm64<false><<<grid, 256, 0, stream>>>(xin, nullptr, nullptr, nullptr,
                                                        wx[l], xg, M, K, GG);
        }
        // row LN with gxw/gxb
        ln_rows<<<M, 256, 0, stream>>>(xg, gxw + l * GG, gxb + l * GG);

        const float* wh_l = wh + (long)l * HH * GG;
        for (int t = 0; t < TT; ++t) {
            const float* h_in = (t == 0) ? (h0 + (long)l * BB * HH) : h_state;
            const float* c_in = (t == 0) ? (c0 + (long)l * BB * HH) : c_state;
            {
                dim3 grid(GG / 64, BB / 64);
                gemm64<false><<<grid, 256, 0, stream>>>(h_in, nullptr, nullptr, nullptr,
                                                        wh_l, tmp, BB, HH, GG);
            }
            lstm_cell<<<BB, 384, 0, stream>>>(
                tmp, xg + (long)t * BB * GG, bias + l * GG,
                ghw + l * GG, ghb + l * GG, c_in,
                h_state, c_state, xout + (long)t * BB * HH,
                out_hn + (long)l * BB * HH, out_cn + (long)l * BB * HH,
                (t == TT - 1) ? 1 : 0);
        }
    }
    (void)in_sizes; (void)n_in; (void)out_size; (void)ws_size;
}